// Round 11
// baseline (253.231 us; speedup 1.0000x reference)
//
#include <hip/hip_runtime.h>
#include <hip/hip_bf16.h>
#include <math.h>

typedef __attribute__((ext_vector_type(8))) short bf16x8;
typedef __attribute__((ext_vector_type(4))) float f32x4;
typedef __attribute__((ext_vector_type(16))) float f32x16;
typedef __attribute__((ext_vector_type(4))) unsigned u32x4;

#define MFMA16(a, b, c) __builtin_amdgcn_mfma_f32_16x16x32_bf16((a), (b), (c), 0, 0, 0)
#define MFMA32(a, b, c) __builtin_amdgcn_mfma_f32_32x32x16_bf16((a), (b), (c), 0, 0, 0)

typedef const __attribute__((address_space(1))) void* gas_ptr;
typedef __attribute__((address_space(3))) void* las_ptr;

#define QK_SCALE 0.18033688011112042f  // 0.125 * log2(e), folded into Q

__device__ __forceinline__ unsigned pack_bf16(float a, float b) {
    unsigned ua = (unsigned)__bfloat16_as_ushort(__float2bfloat16(a));
    unsigned ub = (unsigned)__bfloat16_as_ushort(__float2bfloat16(b));
    return ua | (ub << 16);
}

// ---------------------------------------------------------------------------
// Batched transpose + fp32 -> bf16 convert for all 4 weights (1 launch).
// ---------------------------------------------------------------------------
__global__ __launch_bounds__(256)
void transpose_all(const float* __restrict__ qkv_w, const float* __restrict__ proj_w,
                   const float* __restrict__ ffn_w1, const float* __restrict__ ffn_w2,
                   __hip_bfloat16* __restrict__ wqkv, __hip_bfloat16* __restrict__ wproj,
                   __hip_bfloat16* __restrict__ wff1, __hip_bfloat16* __restrict__ wff2)
{
    const int bid = blockIdx.x;
    const float* in; __hip_bfloat16* out; int K, N, r;
    if (bid < 3072)      { in = qkv_w;  out = wqkv;  K = 1024; N = 3072; r = bid;        }
    else if (bid < 4096) { in = proj_w; out = wproj; K = 1024; N = 1024; r = bid - 3072; }
    else if (bid < 8192) { in = ffn_w1; out = wff1;  K = 1024; N = 4096; r = bid - 4096; }
    else                 { in = ffn_w2; out = wff2;  K = 4096; N = 1024; r = bid - 8192; }
    const int ncols = N >> 5;
    const int n0 = (r % ncols) * 32, k0 = (r / ncols) * 32;

    __shared__ float t[32][33];
    const int tx = threadIdx.x & 31, ty = threadIdx.x >> 5;
    #pragma unroll
    for (int j = 0; j < 32; j += 8)
        t[ty + j][tx] = in[(size_t)(k0 + ty + j) * N + n0 + tx];
    __syncthreads();
    #pragma unroll
    for (int j = 0; j < 32; j += 8)
        out[(size_t)(n0 + ty + j) * K + k0 + tx] = __float2bfloat16(t[tx][ty + j]);
}

// ---------------------------------------------------------------------------
// LayerNorm over D=1024, one block per row, fp32 in -> bf16 out
// ---------------------------------------------------------------------------
__global__ __launch_bounds__(256)
void ln_kernel(const float* __restrict__ in, const float* __restrict__ w,
               const float* __restrict__ b, __hip_bfloat16* __restrict__ out)
{
    const int row = blockIdx.x;
    const int tid = threadIdx.x;
    const float4 v = reinterpret_cast<const float4*>(in + (size_t)row * 1024)[tid];
    float s  = v.x + v.y + v.z + v.w;
    float s2 = v.x * v.x + v.y * v.y + v.z * v.z + v.w * v.w;
    #pragma unroll
    for (int off = 32; off > 0; off >>= 1) {
        s  += __shfl_down(s,  off);
        s2 += __shfl_down(s2, off);
    }
    __shared__ float red[8];
    const int wv = tid >> 6, ln = tid & 63;
    if (ln == 0) { red[wv] = s; red[4 + wv] = s2; }
    __syncthreads();
    s  = red[0] + red[1] + red[2] + red[3];
    s2 = red[4] + red[5] + red[6] + red[7];
    const float mu   = s * (1.0f / 1024.0f);
    const float var  = s2 * (1.0f / 1024.0f) - mu * mu;
    const float rstd = rsqrtf(var + 1e-5f);
    const float4 wv4 = reinterpret_cast<const float4*>(w)[tid];
    const float4 bv4 = reinterpret_cast<const float4*>(b)[tid];
    const size_t o = (size_t)row * 1024 + tid * 4;
    out[o + 0] = __float2bfloat16((v.x - mu) * rstd * wv4.x + bv4.x);
    out[o + 1] = __float2bfloat16((v.y - mu) * rstd * wv4.y + bv4.y);
    out[o + 2] = __float2bfloat16((v.z - mu) * rstd * wv4.z + bv4.z);
    out[o + 3] = __float2bfloat16((v.w - mu) * rstd * wv4.w + bv4.w);
}

// ---------------------------------------------------------------------------
// Pipelined GEMM: 128x128 tile, BK=32, 4 waves, 3-slot LDS ring (48 KiB).
// MODE 2: bf16 out + exact GELU + bias (staged coalesced)
// MODE 3: QKV: q cols (<1024) pre-scaled by QK_SCALE; q|k -> C0 (ld 2048);
//         n0>=2048 -> V^T via LDS transpose-gather -> dense stores
// ---------------------------------------------------------------------------
template<int MODE>
__global__ __launch_bounds__(256, 3)
void gemm128p(const __hip_bfloat16* __restrict__ A,
              const __hip_bfloat16* __restrict__ Bt,
              const float* __restrict__ bias,
              void* __restrict__ C0, void* __restrict__ C1,
              int N, int K)
{
    constexpr int SLOT = 8192;
    __shared__ __align__(16) __hip_bfloat16 lds[3 * SLOT];

    const int tid  = threadIdx.x;
    const int lane = tid & 63;
    const int w    = tid >> 6;
    const int wr   = w >> 1, wc = w & 1;
    const int fr   = lane & 15, fq = lane >> 4;

    const int nwg = gridDim.x * gridDim.y;
    int flat = blockIdx.y * gridDim.x + blockIdx.x;
    flat = (flat & 7) * (nwg >> 3) + (flat >> 3);
    const int bx = flat % gridDim.x, by = flat / gridDim.x;
    const int m0 = by * 128, n0 = bx * 128;
    const int NT = K >> 5;

    const int prc = w * 8 + (lane >> 3);
    const int ch  = lane & 7;
    const __hip_bfloat16* aS[2];
    const __hip_bfloat16* bS[2];
    #pragma unroll
    for (int j = 0; j < 2; ++j) {
        const int pr  = prc + 32 * j;
        const int v   = ch ^ (pr & 7);
        const int row = 2 * pr + (v >> 2);
        const int col = 8 * (v & 3);
        aS[j] = A  + (size_t)(m0 + row) * K + col;
        bS[j] = Bt + (size_t)(n0 + row) * K + col;
    }

    auto stage = [&](int kt, int s) {
        __hip_bfloat16* LA = &lds[s * SLOT];
        __hip_bfloat16* LB = LA + 4096;
        #pragma unroll
        for (int j = 0; j < 2; ++j) {
            __builtin_amdgcn_global_load_lds((gas_ptr)(const void*)(aS[j] + kt * 32),
                                             (las_ptr)(void*)(LA + w * 512 + j * 2048), 16, 0, 0);
            __builtin_amdgcn_global_load_lds((gas_ptr)(const void*)(bS[j] + kt * 32),
                                             (las_ptr)(void*)(LB + w * 512 + j * 2048), 16, 0, 0);
        }
    };

    f32x4 acc[4][4] = {};

    stage(0, 0);
    stage(1, 1);
    int sl = 0, sp = 2;

    for (int kt = 0; kt < NT; ++kt) {
        if (kt + 1 < NT)
            asm volatile("s_waitcnt vmcnt(4) lgkmcnt(0)" ::: "memory");
        else
            asm volatile("s_waitcnt vmcnt(0) lgkmcnt(0)" ::: "memory");
        __builtin_amdgcn_s_barrier();
        __builtin_amdgcn_sched_barrier(0);

        if (kt + 2 < NT) stage(kt + 2, sp);

        const __hip_bfloat16* LA = &lds[sl * SLOT];
        const __hip_bfloat16* LB = LA + 4096;
        bf16x8 af[4], bg[4];
        #pragma unroll
        for (int m = 0; m < 4; ++m) {
            const int r = wr * 64 + m * 16 + fr;
            af[m] = *reinterpret_cast<const bf16x8*>(
                &LA[(r >> 1) * 64 + (((r & 1) * 32 + fq * 8) ^ (((r >> 1) & 7) * 8))]);
        }
        #pragma unroll
        for (int n = 0; n < 4; ++n) {
            const int r = wc * 64 + n * 16 + fr;
            bg[n] = *reinterpret_cast<const bf16x8*>(
                &LB[(r >> 1) * 64 + (((r & 1) * 32 + fq * 8) ^ (((r >> 1) & 7) * 8))]);
        }

        __builtin_amdgcn_s_setprio(1);
        #pragma unroll
        for (int m = 0; m < 4; ++m)
            #pragma unroll
            for (int n = 0; n < 4; ++n)
                acc[m][n] = MFMA16(af[m], bg[n], acc[m][n]);
        __builtin_amdgcn_s_setprio(0);

        sl = (sl == 2) ? 0 : sl + 1;
        sp = (sp == 2) ? 0 : sp + 1;
    }

    // ---- bf16 epilogues: stage tile in swizzled LDS, write back coalesced ----
    __syncthreads();
    ushort* E = reinterpret_cast<ushort*>(lds);
    auto eaddr = [](int r, int c16) { return r * 128 + (((c16) ^ ((r >> 3) & 15)) << 3); };

    const float qsc = (MODE == 3 && n0 < 1024) ? QK_SCALE : 1.0f;
    #pragma unroll
    for (int n = 0; n < 4; ++n) {
        const int col = wc * 64 + n * 16 + fr;
        const float bv = bias[n0 + col];
        #pragma unroll
        for (int m = 0; m < 4; ++m) {
            #pragma unroll
            for (int i = 0; i < 4; ++i) {
                const int row = wr * 64 + m * 16 + fq * 4 + i;
                float v = acc[m][n][i] + bv;
                if (MODE == 2) v = 0.5f * v * (1.0f + erff(v * 0.70710678118654752f));
                if (MODE == 3) v *= qsc;
                E[eaddr(row, col >> 3) + (col & 7)] =
                    __bfloat16_as_ushort(__float2bfloat16(v));
            }
        }
    }
    __syncthreads();

    if (MODE == 3 && n0 >= 2048) {
        const int bq    = m0 >> 11;
        const int lbase = m0 & 2047;
        const int hcb   = n0 - 2048;
        #pragma unroll
        for (int p = 0; p < 8; ++p) {
            const int id  = p * 256 + tid;
            const int hcl = id >> 4;
            const int lc  = id & 15;
            u32x4 pkt;
            #pragma unroll
            for (int k2 = 0; k2 < 4; ++k2) {
                const int l0 = lc * 8 + k2 * 2;
                const unsigned a = E[eaddr(l0,     hcl >> 3) + (hcl & 7)];
                const unsigned b = E[eaddr(l0 + 1, hcl >> 3) + (hcl & 7)];
                pkt[k2] = a | (b << 16);
            }
            *reinterpret_cast<u32x4*>(
                &reinterpret_cast<__hip_bfloat16*>(C1)
                    [((size_t)(bq * 1024 + hcb + hcl) << 11) + lbase + lc * 8]) = pkt;
        }
        return;
    }

    const size_t ldC = (MODE == 3) ? 2048 : (size_t)N;
    __hip_bfloat16* Cb = reinterpret_cast<__hip_bfloat16*>(C0);
    #pragma unroll
    for (int p = 0; p < 8; ++p) {
        const int id  = p * 256 + tid;
        const int row = id >> 4;
        const int c16 = id & 15;
        const bf16x8 vv = *reinterpret_cast<const bf16x8*>(&E[eaddr(row, c16)]);
        *reinterpret_cast<bf16x8*>(&Cb[(size_t)(m0 + row) * ldC + n0 + c16 * 8]) = vv;
    }
}

// ---------------------------------------------------------------------------
// gemm256g (FFN1): 256x256 tile, 8 waves, BK=32, 4-slot LDS ring (128 KiB),
// 2 phases/K-tile, counted vmcnt(8), staged coalesced epilogue (bf16 + GELU).
// ---------------------------------------------------------------------------
__global__ __launch_bounds__(512, 1)
void gemm256g(const __hip_bfloat16* __restrict__ A,
              const __hip_bfloat16* __restrict__ Bt,
              const float* __restrict__ bias,
              __hip_bfloat16* __restrict__ C0,
              int N, int K)
{
    constexpr int SLOT = 16384;
    __shared__ __align__(16) __hip_bfloat16 lds[4 * SLOT];

    const int tid  = threadIdx.x;
    const int lane = tid & 63;
    const int w    = tid >> 6;
    const int wm   = w >> 2, wn = w & 3;
    const int fr   = lane & 15, fq = lane >> 4;

    const int nwg = gridDim.x * gridDim.y;
    int flat = blockIdx.y * gridDim.x + blockIdx.x;
    flat = (flat & 7) * (nwg >> 3) + (flat >> 3);
    const int bx = flat % gridDim.x, by = flat / gridDim.x;
    const int m0 = by * 256, n0 = bx * 256;
    const int NT = K >> 5;

    const __hip_bfloat16* aS[2];
    const __hip_bfloat16* bS[2];
    #pragma unroll
    for (int j = 0; j < 2; ++j) {
        const int c   = tid + 512 * j;
        const int row = c >> 2;
        const int lc  = (c & 3) ^ ((row >> 1) & 3);
        aS[j] = A  + (size_t)(m0 + row) * K + lc * 8;
        bS[j] = Bt + (size_t)(n0 + row) * K + lc * 8;
    }

    auto stageA = [&](int kt) {
        __hip_bfloat16* L = &lds[(kt & 3) * SLOT];
        #pragma unroll
        for (int j = 0; j < 2; ++j)
            __builtin_amdgcn_global_load_lds((gas_ptr)(const void*)(aS[j] + kt * 32),
                                             (las_ptr)(void*)(L + w * 512 + j * 4096), 16, 0, 0);
    };
    auto stageB = [&](int kt) {
        __hip_bfloat16* L = &lds[(kt & 3) * SLOT] + 8192;
        #pragma unroll
        for (int j = 0; j < 2; ++j)
            __builtin_amdgcn_global_load_lds((gas_ptr)(const void*)(bS[j] + kt * 32),
                                             (las_ptr)(void*)(L + w * 512 + j * 4096), 16, 0, 0);
    };

    f32x4 acc[8][4] = {};

    stageA(0); stageB(0);
    stageA(1); stageB(1);
    stageA(2); stageB(2);
    asm volatile("s_waitcnt vmcnt(8)" ::: "memory");
    __builtin_amdgcn_s_barrier();
    __builtin_amdgcn_sched_barrier(0);

    for (int kt = 0; kt < NT; ++kt) {
        const __hip_bfloat16* LA = &lds[(kt & 3) * SLOT];
        const __hip_bfloat16* LB = LA + 8192;
        bf16x8 af[4], bg[4];

        #pragma unroll
        for (int m = 0; m < 4; ++m) {
            const int r = wm * 128 + m * 16 + fr;
            af[m] = *reinterpret_cast<const bf16x8*>(
                &LA[r * 32 + ((fq ^ ((r >> 1) & 3)) << 3)]);
        }
        #pragma unroll
        for (int n = 0; n < 4; ++n) {
            const int r = wn * 64 + n * 16 + fr;
            bg[n] = *reinterpret_cast<const bf16x8*>(
                &LB[r * 32 + ((fq ^ ((r >> 1) & 3)) << 3)]);
        }
        if (kt + 3 < NT) stageA(kt + 3);
        __builtin_amdgcn_sched_barrier(0);
        __builtin_amdgcn_s_barrier();
        asm volatile("s_waitcnt lgkmcnt(0)" ::: "memory");
        __builtin_amdgcn_sched_barrier(0);
        __builtin_amdgcn_s_setprio(1);
        #pragma unroll
        for (int m = 0; m < 4; ++m)
            #pragma unroll
            for (int n = 0; n < 4; ++n)
                acc[m][n] = MFMA16(af[m], bg[n], acc[m][n]);
        __builtin_amdgcn_s_setprio(0);
        __builtin_amdgcn_sched_barrier(0);
        __builtin_amdgcn_s_barrier();

        #pragma unroll
        for (int m = 0; m < 4; ++m) {
            const int r = wm * 128 + 64 + m * 16 + fr;
            af[m] = *reinterpret_cast<const bf16x8*>(
                &LA[r * 32 + ((fq ^ ((r >> 1) & 3)) << 3)]);
        }
        if (kt + 3 < NT) stageB(kt + 3);
        __builtin_amdgcn_sched_barrier(0);
        __builtin_amdgcn_s_barrier();
        asm volatile("s_waitcnt lgkmcnt(0)" ::: "memory");
        __builtin_amdgcn_sched_barrier(0);
        __builtin_amdgcn_s_setprio(1);
        #pragma unroll
        for (int m = 0; m < 4; ++m)
            #pragma unroll
            for (int n = 0; n < 4; ++n)
                acc[4 + m][n] = MFMA16(af[m], bg[n], acc[4 + m][n]);
        __builtin_amdgcn_s_setprio(0);
        __builtin_amdgcn_sched_barrier(0);
        if (kt + 3 < NT)      asm volatile("s_waitcnt vmcnt(8)" ::: "memory");
        else if (kt + 2 < NT) asm volatile("s_waitcnt vmcnt(4)" ::: "memory");
        else                  asm volatile("s_waitcnt vmcnt(0)" ::: "memory");
        __builtin_amdgcn_s_barrier();
    }

    __syncthreads();
    ushort* E = reinterpret_cast<ushort*>(lds);
    auto eaddr = [](int r, int c16) { return r * 256 + (((c16) ^ (r & 31)) << 3); };

    #pragma unroll
    for (int n = 0; n < 4; ++n) {
        const int col = wn * 64 + n * 16 + fr;
        const float bv = bias[n0 + col];
        #pragma unroll
        for (int a = 0; a < 8; ++a) {
            #pragma unroll
            for (int i = 0; i < 4; ++i) {
                const int row = wm * 128 + (a >> 2) * 64 + (a & 3) * 16 + fq * 4 + i;
                float v = acc[a][n][i] + bv;
                v = 0.5f * v * (1.0f + erff(v * 0.70710678118654752f));
                E[eaddr(row, col >> 3) + (col & 7)] =
                    __bfloat16_as_ushort(__float2bfloat16(v));
            }
        }
    }
    __syncthreads();

    #pragma unroll
    for (int p = 0; p < 16; ++p) {
        const int id  = p * 512 + tid;
        const int row = id >> 5;
        const int c16 = id & 31;
        const bf16x8 vv = *reinterpret_cast<const bf16x8*>(&E[eaddr(row, c16)]);
        *reinterpret_cast<bf16x8*>(&C0[(size_t)(m0 + row) * N + n0 + c16 * 8]) = vv;
    }
}

// ---------------------------------------------------------------------------
// gemm_n64: 128x64 tile for the grid-starved N=1024 GEMMs (proj, FFN2).
// ---------------------------------------------------------------------------
__global__ __launch_bounds__(256, 3)
void gemm_n64(const __hip_bfloat16* __restrict__ A,
              const __hip_bfloat16* __restrict__ Bt,
              const float* __restrict__ bias,
              const float* __restrict__ resid,
              float* __restrict__ C0,
              int N, int K)
{
    constexpr int SLOT = 6144;
    __shared__ __align__(16) __hip_bfloat16 lds[3 * SLOT];

    const int tid  = threadIdx.x;
    const int lane = tid & 63;
    const int w    = tid >> 6;
    const int wr   = w >> 1, wc = w & 1;
    const int fr   = lane & 15, fq = lane >> 4;

    const int nwg = gridDim.x * gridDim.y;
    int flat = blockIdx.y * gridDim.x + blockIdx.x;
    flat = (flat & 7) * (nwg >> 3) + (flat >> 3);
    const int bx = flat % gridDim.x, by = flat / gridDim.x;
    const int m0 = by * 128, n0 = bx * 64;
    const int NT = K >> 5;

    const int prc = w * 8 + (lane >> 3);
    const int ch  = lane & 7;
    const __hip_bfloat16* aS[2];
    #pragma unroll
    for (int j = 0; j < 2; ++j) {
        const int pr  = prc + 32 * j;
        const int v   = ch ^ (pr & 7);
        aS[j] = A + (size_t)(m0 + 2 * pr + (v >> 2)) * K + 8 * (v & 3);
    }
    const __hip_bfloat16* bS;
    {
        const int c  = w * 64 + lane;
        const int pr = c >> 3;
        const int v  = (c & 7) ^ (pr & 7);
        bS = Bt + (size_t)(n0 + 2 * pr + (v >> 2)) * K + 8 * (v & 3);
    }

    auto stage = [&](int kt, int s) {
        __hip_bfloat16* LA = &lds[s * SLOT];
        __hip_bfloat16* LB = LA + 4096;
        #pragma unroll
        for (int j = 0; j < 2; ++j)
            __builtin_amdgcn_global_load_lds((gas_ptr)(const void*)(aS[j] + kt * 32),
                                             (las_ptr)(void*)(LA + w * 512 + j * 2048), 16, 0, 0);
        __builtin_amdgcn_global_load_lds((gas_ptr)(const void*)(bS + kt * 32),
                                         (las_ptr)(void*)(LB + w * 512), 16, 0, 0);
    };

    f32x4 acc[4][2] = {};

    stage(0, 0);
    stage(1, 1);
    int sl = 0, sp = 2;

    for (int kt = 0; kt < NT; ++kt) {
        if (kt + 1 < NT)
            asm volatile("s_waitcnt vmcnt(3) lgkmcnt(0)" ::: "memory");
        else
            asm volatile("s_waitcnt vmcnt(0) lgkmcnt(0)" ::: "memory");
        __builtin_amdgcn_s_barrier();
        __builtin_amdgcn_sched_barrier(0);

        if (kt + 2 < NT) stage(kt + 2, sp);

        const __hip_bfloat16* LA = &lds[sl * SLOT];
        const __hip_bfloat16* LB = LA + 4096;
        bf16x8 af[4], bg[2];
        #pragma unroll
        for (int m = 0; m < 4; ++m) {
            const int r = wr * 64 + m * 16 + fr;
            af[m] = *reinterpret_cast<const bf16x8*>(
                &LA[(r >> 1) * 64 + (((r & 1) * 32 + fq * 8) ^ (((r >> 1) & 7) * 8))]);
        }
        #pragma unroll
        for (int n = 0; n < 2; ++n) {
            const int r = wc * 32 + n * 16 + fr;
            bg[n] = *reinterpret_cast<const bf16x8*>(
                &LB[(r >> 1) * 64 + (((r & 1) * 32 + fq * 8) ^ (((r >> 1) & 7) * 8))]);
        }

        __builtin_amdgcn_s_setprio(1);
        #pragma unroll
        for (int m = 0; m < 4; ++m)
            #pragma unroll
            for (int n = 0; n < 2; ++n)
                acc[m][n] = MFMA16(af[m], bg[n], acc[m][n]);
        __builtin_amdgcn_s_setprio(0);

        sl = (sl == 2) ? 0 : sl + 1;
        sp = (sp == 2) ? 0 : sp + 1;
    }

    #pragma unroll
    for (int n = 0; n < 2; ++n) {
        const int col = n0 + wc * 32 + n * 16 + fr;
        const float bv = bias[col];
        #pragma unroll
        for (int m = 0; m < 4; ++m)
            #pragma unroll
            for (int i = 0; i < 4; ++i) {
                const int row = m0 + wr * 64 + m * 16 + fq * 4 + i;
                C0[(size_t)row * N + col] = acc[m][n][i] + bv + resid[(size_t)row * N + col];
            }
    }
}

// ---------------------------------------------------------------------------
// Causal flash attention v3: 32x32x16 MFMA, in-register softmax.
// Block = 2 waves x 32 q (64-q span), KVBLK=64, grid 1024.
// Swapped QK^T: S^T = mfma(K, Q) -> q = lane&31 for S, O, m, l (all per-lane
// scalars, no broadcast shuffles). P -> PV B-fragment via v_permlane32_swap.
// K lds [64 kv][64 d], V^T lds [64 d][64 kv], 16B-chunk XOR (row&7) swizzle.
// O^T staged in LDS -> coalesced 16B output stores.
// ---------------------------------------------------------------------------
__global__ __launch_bounds__(128)
void attn_kernel(const __hip_bfloat16* __restrict__ qk,
                 const __hip_bfloat16* __restrict__ Vt,
                 __hip_bfloat16* __restrict__ out)
{
    const int bid  = blockIdx.x;
    const int xcd  = bid & 7;
    const int rank = bid >> 3;
    const int panel = xcd * 4 + (rank & 3);
    const int qt   = 31 - (rank >> 2);
    const int h = panel & 15, b = panel >> 4;
    const int q0 = qt * 64;

    const int lane = threadIdx.x & 63;
    const int w    = threadIdx.x >> 6;        // 0..1
    const int qv   = lane & 31;               // q column owned by this lane
    const int hi   = lane >> 5;               // k-slice half
    const int qrow = q0 + w * 32 + qv;

    __shared__ __align__(16) __hip_bfloat16 Klds[2][64 * 64];
    __shared__ __align__(16) __hip_bfloat16 Vlds[2][64 * 64];

    // Q as B-fragments: step s needs d = s*16 + hi*8 .. +8
    bf16x8 qf[4];
    {
        const __hip_bfloat16* qp = qk + ((size_t)(b * 2048 + qrow) << 11) + h * 64 + hi * 8;
        #pragma unroll
        for (int s = 0; s < 4; ++s)
            qf[s] = *reinterpret_cast<const bf16x8*>(qp + s * 16);
    }

    // staging: 512 chunks of 16B per tile; thread covers c = w*64 + j*128 + lane
    const __hip_bfloat16* Kg[4];
    const __hip_bfloat16* Vg[4];
    #pragma unroll
    for (int j = 0; j < 4; ++j) {
        const int c  = w * 64 + j * 128 + lane;
        const int r  = c >> 3;
        const int lc = (c & 7) ^ (r & 7);
        Kg[j] = qk + ((size_t)(b * 2048 + r) << 11) + 1024 + h * 64 + lc * 8;
        Vg[j] = Vt + ((size_t)(b * 1024 + h * 64 + r) << 11) + lc * 8;
    }

    auto stage = [&](int kv0, int bufi) {
        #pragma unroll
        for (int j = 0; j < 4; ++j) {
            __builtin_amdgcn_global_load_lds(
                (gas_ptr)(const void*)(Kg[j] + ((size_t)kv0 << 11)),
                (las_ptr)(void*)&Klds[bufi][(w * 64 + j * 128) * 8], 16, 0, 0);
            __builtin_amdgcn_global_load_lds(
                (gas_ptr)(const void*)(Vg[j] + kv0),
                (las_ptr)(void*)&Vlds[bufi][(w * 64 + j * 128) * 8], 16, 0, 0);
        }
    };

    float m_run = -1e30f, l_run = 0.0f;
    f32x16 o0 = {}, o1 = {};

    const int ntiles = qt + 1;
    stage(0, 0);
    int cur = 0;

    for (int t = 0; t < ntiles; ++t) {
        const int kv0 = t << 6;
        __syncthreads();
        if (t + 1 < ntiles) stage((t + 1) << 6, cur ^ 1);

        const __hip_bfloat16* Kl = &Klds[cur][0];
        const __hip_bfloat16* Vl = &Vlds[cur][0];

        // ---- S^T = K * Q^T : 2 kv blocks x (K=64 -> 4 mfma steps) ----
        f32x16 s0 = {}, s1 = {};
        #pragma unroll
        for (int s = 0; s < 4; ++s) {
            const int lc = 2 * s + hi;
            const int ph = (lc ^ (qv & 7)) << 3;
            const bf16x8 k0 = *reinterpret_cast<const bf16x8*>(&Kl[qv * 64 + ph]);
            const bf16x8 k1 = *reinterpret_cast<const bf16x8*>(&Kl[(32 + qv) * 64 + ph]);
            s0 = MFMA32(k0, qf[s], s0);
            s1 = MFMA32(k1, qf[s], s1);
        }

        // ---- mask (diagonal tile only) + in-lane max ----
        float pm = -1e30f;
        if (t == ntiles - 1) {
            #pragma unroll
            for (int r = 0; r < 16; ++r) {
                const int kvl = (r & 3) + 8 * (r >> 2) + 4 * hi;
                s0[r] = (kv0 + kvl      <= qrow) ? s0[r] : -1e30f;
                s1[r] = (kv0 + kvl + 32 <= qrow) ? s1[r] : -1e30f;
                pm = fmaxf(pm, fmaxf(s0[r], s1[r]));
            }
        } else {
            #pragma unroll
            for (int r = 0; r < 16; ++r)
                pm = fmaxf(pm, fmaxf(s0[r], s1[r]));
        }
        pm = fmaxf(pm, __shfl_xor(pm, 32));

        // ---- defer-max rescale (per-lane scalar corr, no broadcasts) ----
        if (!__all(pm <= m_run + 8.0f)) {
            const float mnew = fmaxf(m_run, pm);
            const float corr = exp2f(m_run - mnew);
            m_run = mnew;
            l_run *= corr;
            #pragma unroll
            for (int r = 0; r < 16; ++r) { o0[r] *= corr; o1[r] *= corr; }
        }

        // ---- P = exp2(S - m), pack pairs ----
        float rs = 0.0f;
        unsigned pk0[8], pk1[8];
        #pragma unroll
        for (int j = 0; j < 8; ++j) {
            const float a0 = exp2f(s0[2 * j]     - m_run);
            const float a1 = exp2f(s0[2 * j + 1] - m_run);
            const float b0 = exp2f(s1[2 * j]     - m_run);
            const float b1 = exp2f(s1[2 * j + 1] - m_run);
            rs += (a0 + a1) + (b0 + b1);
            pk0[j] = pack_bf16(a0, a1);
            pk1[j] = pack_bf16(b0, b1);
        }
        rs += __shfl_xor(rs, 32);
        l_run += rs;

        // ---- PV: B_s via permlane32_swap, A = V^T rows ----
        #pragma unroll
        for (int s = 0; s < 4; ++s) {
            const int s2 = (s & 1) * 4;
            unsigned e0, e1, e2, e3;
            if (s < 2) { e0 = pk0[s2]; e1 = pk0[s2 + 1]; e2 = pk0[s2 + 2]; e3 = pk0[s2 + 3]; }
            else       { e0 = pk1[s2]; e1 = pk1[s2 + 1]; e2 = pk1[s2 + 2]; e3 = pk1[s2 + 3]; }
            asm("v_permlane32_swap_b32 %0, %1" : "+v"(e0), "+v"(e2));
            asm("v_permlane32_swap_b32 %0, %1" : "+v"(e1), "+v"(e3));
            u32x4 B; B[0] = e0; B[1] = e1; B[2] = e2; B[3] = e3;
            const bf16x8 pb = __builtin_bit_cast(bf16x8, B);

            const int lc = 2 * s + hi;
            const int ph = (lc ^ (qv & 7)) << 3;
            const bf16x8 v0 = *reinterpret_cast<const bf16x8*>(&Vl[qv * 64 + ph]);
            const bf16x8 v1 = *reinterpret_cast<const bf16x8*>(&Vl[(32 + qv) * 64 + ph]);
            o0 = MFMA32(v0, pb, o0);
            o1 = MFMA32(v1, pb, o1);
        }
        cur ^= 1;
    }

    // ---- normalize + stage O^T in LDS -> coalesced output stores ----
    const float inv = 1.0f / l_run;
    __syncthreads();                       // K/V reads done; reuse Klds as O stage
    ushort* OS = reinterpret_cast<ushort*>(&Klds[0][0]);  // [64 q][72 d-stride]
    const int orow = w * 32 + qv;
    #pragma unroll
    for (int j = 0; j < 8; ++j) {
        const int d = 2 * (j & 1) + 8 * (j >> 1) + 4 * hi;
        *reinterpret_cast<unsigned*>(&OS[orow * 72 + d]) =
            pack_bf16(o0[2 * j] * inv, o0[2 * j + 1] * inv);
        *reinterpret_cast<unsigned*>(&OS[orow * 72 + d + 32]) =
            pack_bf16(o1[2 * j] * inv, o1[2 * j + 1] * inv);
    }
    __syncthreads();
    #pragma unroll
    for (int p = 0; p < 4; ++p) {
        const int c   = p * 128 + threadIdx.x;
        const int row = c >> 3;
        const int ch  = c & 7;
        const bf16x8 vv = *reinterpret_cast<const bf16x8*>(&OS[row * 72 + ch * 8]);
        *reinterpret_cast<bf16x8*>(
            &out[(size_t)(b * 2048 + q0 + row) * 1024 + h * 64 + ch * 8]) = vv;
    }
}

// ---------------------------------------------------------------------------
extern "C" void kernel_launch(void* const* d_in, const int* in_sizes, int n_in,
                              void* d_out, int out_size, void* d_ws, size_t ws_size,
                              hipStream_t stream)
{
    (void)in_sizes; (void)n_in; (void)out_size; (void)ws_size;
    const float* x      = (const float*)d_in[0];
    const float* ln1_w  = (const float*)d_in[2];
    const float* ln1_b  = (const float*)d_in[3];
    const float* qkv_w  = (const float*)d_in[4];
    const float* qkv_b  = (const float*)d_in[5];
    const float* proj_w = (const float*)d_in[6];
    const float* proj_b = (const float*)d_in[7];
    const float* ln2_w  = (const float*)d_in[8];
    const float* ln2_b  = (const float*)d_in[9];
    const float* ffn_w1 = (const float*)d_in[10];
    const float* ffn_b1 = (const float*)d_in[11];
    const float* ffn_w2 = (const float*)d_in[12];
    const float* ffn_b2 = (const float*)d_in[13];
    float* outp = (float*)d_out;

    char* ws = (char*)d_ws;
    size_t off = 0;
    auto take = [&](size_t bytes) -> char* {
        char* p = ws + off;
        off += (bytes + 255) & ~(size_t)255;
        return p;
    };
    __hip_bfloat16* wqkv  = (__hip_bfloat16*)take((size_t)3072 * 1024 * 2);  // 6 MB
    __hip_bfloat16* wproj = (__hip_bfloat16*)take((size_t)1024 * 1024 * 2);  // 2 MB
    __hip_bfloat16* wff1  = (__hip_bfloat16*)take((size_t)4096 * 1024 * 2);  // 8 MB
    __hip_bfloat16* wff2  = (__hip_bfloat16*)take((size_t)1024 * 4096 * 2);  // 8 MB
    float*          hbuf  = (float*)take((size_t)4096 * 1024 * 4);           // 16 MB
    __hip_bfloat16* xn    = (__hip_bfloat16*)take((size_t)4096 * 1024 * 2);  // 8 MB
    __hip_bfloat16* qkb   = (__hip_bfloat16*)take((size_t)4096 * 2048 * 2);  // 16 MB
    __hip_bfloat16* Vt    = (__hip_bfloat16*)take((size_t)2048 * 2048 * 2);  // 8 MB
    __hip_bfloat16* attn  = (__hip_bfloat16*)take((size_t)4096 * 1024 * 2);  // 8 MB
    __hip_bfloat16* ffn1  = qkb;  // FFN1 out (32 MB) reuses qkb+Vt+attn

    transpose_all<<<12288, 256, 0, stream>>>(qkv_w, proj_w, ffn_w1, ffn_w2,
                                             wqkv, wproj, wff1, wff2);
    // LN1
    ln_kernel<<<4096, 256, 0, stream>>>(x, ln1_w, ln1_b, xn);
    // QKV (q pre-scaled by QK_SCALE; q|k -> qkb, V^T -> Vt)
    gemm128p<3><<<dim3(24, 32), 256, 0, stream>>>(
        xn, wqkv, qkv_b, qkb, Vt, 3072, 1024);
    // Attention v3 (32x32 MFMA, in-register softmax)
    attn_kernel<<<1024, 128, 0, stream>>>(qkb, Vt, attn);
    // proj + residual(x) -> h (fp32)
    gemm_n64<<<dim3(16, 32), 256, 0, stream>>>(
        attn, wproj, proj_b, x, hbuf, 1024, 1024);
    // LN2 -> y
    ln_kernel<<<4096, 256, 0, stream>>>(hbuf, ln2_w, ln2_b, xn);
    // FFN1 + exact GELU (256² pipelined core + staged epilogue)
    gemm256g<<<dim3(16, 16), 512, 0, stream>>>(
        xn, wff1, ffn_b1, ffn1, 4096, 1024);
    // FFN2 + bias + residual(h) -> out (fp32)
    gemm_n64<<<dim3(16, 32), 256, 0, stream>>>(
        ffn1, wff2, ffn_b2, hbuf, outp, 1024, 4096);
}

// Round 12
// 243.780 us; speedup vs baseline: 1.0388x; 1.0388x over previous
//
#include <hip/hip_runtime.h>
#include <hip/hip_bf16.h>
#include <math.h>

typedef __attribute__((ext_vector_type(8))) short bf16x8;
typedef __attribute__((ext_vector_type(4))) float f32x4;
typedef __attribute__((ext_vector_type(4))) unsigned u32x4;

#define MFMA16(a, b, c) __builtin_amdgcn_mfma_f32_16x16x32_bf16((a), (b), (c), 0, 0, 0)

typedef const __attribute__((address_space(1))) void* gas_ptr;
typedef __attribute__((address_space(3))) void* las_ptr;

#define QK_SCALE 0.18033688011112042f  // 0.125 * log2(e), folded into Q

__device__ __forceinline__ unsigned pack_bf16(float a, float b) {
    unsigned ua = (unsigned)__bfloat16_as_ushort(__float2bfloat16(a));
    unsigned ub = (unsigned)__bfloat16_as_ushort(__float2bfloat16(b));
    return ua | (ub << 16);
}

// ---------------------------------------------------------------------------
// Batched transpose + fp32 -> bf16 convert for all 4 weights (1 launch).
// ---------------------------------------------------------------------------
__global__ __launch_bounds__(256)
void transpose_all(const float* __restrict__ qkv_w, const float* __restrict__ proj_w,
                   const float* __restrict__ ffn_w1, const float* __restrict__ ffn_w2,
                   __hip_bfloat16* __restrict__ wqkv, __hip_bfloat16* __restrict__ wproj,
                   __hip_bfloat16* __restrict__ wff1, __hip_bfloat16* __restrict__ wff2)
{
    const int bid = blockIdx.x;
    const float* in; __hip_bfloat16* out; int K, N, r;
    if (bid < 3072)      { in = qkv_w;  out = wqkv;  K = 1024; N = 3072; r = bid;        }
    else if (bid < 4096) { in = proj_w; out = wproj; K = 1024; N = 1024; r = bid - 3072; }
    else if (bid < 8192) { in = ffn_w1; out = wff1;  K = 1024; N = 4096; r = bid - 4096; }
    else                 { in = ffn_w2; out = wff2;  K = 4096; N = 1024; r = bid - 8192; }
    const int ncols = N >> 5;
    const int n0 = (r % ncols) * 32, k0 = (r / ncols) * 32;

    __shared__ float t[32][33];
    const int tx = threadIdx.x & 31, ty = threadIdx.x >> 5;
    #pragma unroll
    for (int j = 0; j < 32; j += 8)
        t[ty + j][tx] = in[(size_t)(k0 + ty + j) * N + n0 + tx];
    __syncthreads();
    #pragma unroll
    for (int j = 0; j < 32; j += 8)
        out[(size_t)(n0 + ty + j) * K + k0 + tx] = __float2bfloat16(t[tx][ty + j]);
}

// ---------------------------------------------------------------------------
// LayerNorm over D=1024, one block per row, fp32 in -> bf16 out
// ---------------------------------------------------------------------------
__global__ __launch_bounds__(256)
void ln_kernel(const float* __restrict__ in, const float* __restrict__ w,
               const float* __restrict__ b, __hip_bfloat16* __restrict__ out)
{
    const int row = blockIdx.x;
    const int tid = threadIdx.x;
    const float4 v = reinterpret_cast<const float4*>(in + (size_t)row * 1024)[tid];
    float s  = v.x + v.y + v.z + v.w;
    float s2 = v.x * v.x + v.y * v.y + v.z * v.z + v.w * v.w;
    #pragma unroll
    for (int off = 32; off > 0; off >>= 1) {
        s  += __shfl_down(s,  off);
        s2 += __shfl_down(s2, off);
    }
    __shared__ float red[8];
    const int wv = tid >> 6, ln = tid & 63;
    if (ln == 0) { red[wv] = s; red[4 + wv] = s2; }
    __syncthreads();
    s  = red[0] + red[1] + red[2] + red[3];
    s2 = red[4] + red[5] + red[6] + red[7];
    const float mu   = s * (1.0f / 1024.0f);
    const float var  = s2 * (1.0f / 1024.0f) - mu * mu;
    const float rstd = rsqrtf(var + 1e-5f);
    const float4 wv4 = reinterpret_cast<const float4*>(w)[tid];
    const float4 bv4 = reinterpret_cast<const float4*>(b)[tid];
    const size_t o = (size_t)row * 1024 + tid * 4;
    out[o + 0] = __float2bfloat16((v.x - mu) * rstd * wv4.x + bv4.x);
    out[o + 1] = __float2bfloat16((v.y - mu) * rstd * wv4.y + bv4.y);
    out[o + 2] = __float2bfloat16((v.z - mu) * rstd * wv4.z + bv4.z);
    out[o + 3] = __float2bfloat16((v.w - mu) * rstd * wv4.w + bv4.w);
}

// ---------------------------------------------------------------------------
// Pipelined GEMM: 128x128 tile, BK=32, 4 waves, 3-slot LDS ring (48 KiB).
// MODE 2: bf16 out + exact GELU + bias (staged coalesced)
// MODE 3: QKV: q cols (<1024) pre-scaled by QK_SCALE; q|k -> C0 (ld 2048);
//         n0>=2048 -> V^T via LDS transpose-gather -> dense stores
// ---------------------------------------------------------------------------
template<int MODE>
__global__ __launch_bounds__(256, 3)
void gemm128p(const __hip_bfloat16* __restrict__ A,
              const __hip_bfloat16* __restrict__ Bt,
              const float* __restrict__ bias,
              void* __restrict__ C0, void* __restrict__ C1,
              int N, int K)
{
    constexpr int SLOT = 8192;
    __shared__ __align__(16) __hip_bfloat16 lds[3 * SLOT];

    const int tid  = threadIdx.x;
    const int lane = tid & 63;
    const int w    = tid >> 6;
    const int wr   = w >> 1, wc = w & 1;
    const int fr   = lane & 15, fq = lane >> 4;

    const int nwg = gridDim.x * gridDim.y;
    int flat = blockIdx.y * gridDim.x + blockIdx.x;
    flat = (flat & 7) * (nwg >> 3) + (flat >> 3);
    const int bx = flat % gridDim.x, by = flat / gridDim.x;
    const int m0 = by * 128, n0 = bx * 128;
    const int NT = K >> 5;

    const int prc = w * 8 + (lane >> 3);
    const int ch  = lane & 7;
    const __hip_bfloat16* aS[2];
    const __hip_bfloat16* bS[2];
    #pragma unroll
    for (int j = 0; j < 2; ++j) {
        const int pr  = prc + 32 * j;
        const int v   = ch ^ (pr & 7);
        const int row = 2 * pr + (v >> 2);
        const int col = 8 * (v & 3);
        aS[j] = A  + (size_t)(m0 + row) * K + col;
        bS[j] = Bt + (size_t)(n0 + row) * K + col;
    }

    auto stage = [&](int kt, int s) {
        __hip_bfloat16* LA = &lds[s * SLOT];
        __hip_bfloat16* LB = LA + 4096;
        #pragma unroll
        for (int j = 0; j < 2; ++j) {
            __builtin_amdgcn_global_load_lds((gas_ptr)(const void*)(aS[j] + kt * 32),
                                             (las_ptr)(void*)(LA + w * 512 + j * 2048), 16, 0, 0);
            __builtin_amdgcn_global_load_lds((gas_ptr)(const void*)(bS[j] + kt * 32),
                                             (las_ptr)(void*)(LB + w * 512 + j * 2048), 16, 0, 0);
        }
    };

    f32x4 acc[4][4] = {};

    stage(0, 0);
    stage(1, 1);
    int sl = 0, sp = 2;

    for (int kt = 0; kt < NT; ++kt) {
        if (kt + 1 < NT)
            asm volatile("s_waitcnt vmcnt(4) lgkmcnt(0)" ::: "memory");
        else
            asm volatile("s_waitcnt vmcnt(0) lgkmcnt(0)" ::: "memory");
        __builtin_amdgcn_s_barrier();
        __builtin_amdgcn_sched_barrier(0);

        if (kt + 2 < NT) stage(kt + 2, sp);

        const __hip_bfloat16* LA = &lds[sl * SLOT];
        const __hip_bfloat16* LB = LA + 4096;
        bf16x8 af[4], bg[4];
        #pragma unroll
        for (int m = 0; m < 4; ++m) {
            const int r = wr * 64 + m * 16 + fr;
            af[m] = *reinterpret_cast<const bf16x8*>(
                &LA[(r >> 1) * 64 + (((r & 1) * 32 + fq * 8) ^ (((r >> 1) & 7) * 8))]);
        }
        #pragma unroll
        for (int n = 0; n < 4; ++n) {
            const int r = wc * 64 + n * 16 + fr;
            bg[n] = *reinterpret_cast<const bf16x8*>(
                &LB[(r >> 1) * 64 + (((r & 1) * 32 + fq * 8) ^ (((r >> 1) & 7) * 8))]);
        }

        __builtin_amdgcn_s_setprio(1);
        #pragma unroll
        for (int m = 0; m < 4; ++m)
            #pragma unroll
            for (int n = 0; n < 4; ++n)
                acc[m][n] = MFMA16(af[m], bg[n], acc[m][n]);
        __builtin_amdgcn_s_setprio(0);

        sl = (sl == 2) ? 0 : sl + 1;
        sp = (sp == 2) ? 0 : sp + 1;
    }

    // ---- bf16 epilogues: stage tile in swizzled LDS, write back coalesced ----
    __syncthreads();
    ushort* E = reinterpret_cast<ushort*>(lds);
    auto eaddr = [](int r, int c16) { return r * 128 + (((c16) ^ ((r >> 3) & 15)) << 3); };

    const float qsc = (MODE == 3 && n0 < 1024) ? QK_SCALE : 1.0f;
    #pragma unroll
    for (int n = 0; n < 4; ++n) {
        const int col = wc * 64 + n * 16 + fr;
        const float bv = bias[n0 + col];
        #pragma unroll
        for (int m = 0; m < 4; ++m) {
            #pragma unroll
            for (int i = 0; i < 4; ++i) {
                const int row = wr * 64 + m * 16 + fq * 4 + i;
                float v = acc[m][n][i] + bv;
                if (MODE == 2) v = 0.5f * v * (1.0f + erff(v * 0.70710678118654752f));
                if (MODE == 3) v *= qsc;
                E[eaddr(row, col >> 3) + (col & 7)] =
                    __bfloat16_as_ushort(__float2bfloat16(v));
            }
        }
    }
    __syncthreads();

    if (MODE == 3 && n0 >= 2048) {
        const int bq    = m0 >> 11;
        const int lbase = m0 & 2047;
        const int hcb   = n0 - 2048;
        #pragma unroll
        for (int p = 0; p < 8; ++p) {
            const int id  = p * 256 + tid;
            const int hcl = id >> 4;
            const int lc  = id & 15;
            u32x4 pkt;
            #pragma unroll
            for (int k2 = 0; k2 < 4; ++k2) {
                const int l0 = lc * 8 + k2 * 2;
                const unsigned a = E[eaddr(l0,     hcl >> 3) + (hcl & 7)];
                const unsigned b = E[eaddr(l0 + 1, hcl >> 3) + (hcl & 7)];
                pkt[k2] = a | (b << 16);
            }
            *reinterpret_cast<u32x4*>(
                &reinterpret_cast<__hip_bfloat16*>(C1)
                    [((size_t)(bq * 1024 + hcb + hcl) << 11) + lbase + lc * 8]) = pkt;
        }
        return;
    }

    const size_t ldC = (MODE == 3) ? 2048 : (size_t)N;
    __hip_bfloat16* Cb = reinterpret_cast<__hip_bfloat16*>(C0);
    #pragma unroll
    for (int p = 0; p < 8; ++p) {
        const int id  = p * 256 + tid;
        const int row = id >> 4;
        const int c16 = id & 15;
        const bf16x8 vv = *reinterpret_cast<const bf16x8*>(&E[eaddr(row, c16)]);
        *reinterpret_cast<bf16x8*>(&Cb[(size_t)(m0 + row) * ldC + n0 + c16 * 8]) = vv;
    }
}

// ---------------------------------------------------------------------------
// gemm256g (FFN1): 256x256 tile, 8 waves, BK=32, 4-slot LDS ring (128 KiB),
// 2 phases/K-tile, counted vmcnt(8), staged coalesced epilogue (bf16 + GELU).
// ---------------------------------------------------------------------------
__global__ __launch_bounds__(512, 1)
void gemm256g(const __hip_bfloat16* __restrict__ A,
              const __hip_bfloat16* __restrict__ Bt,
              const float* __restrict__ bias,
              __hip_bfloat16* __restrict__ C0,
              int N, int K)
{
    constexpr int SLOT = 16384;
    __shared__ __align__(16) __hip_bfloat16 lds[4 * SLOT];

    const int tid  = threadIdx.x;
    const int lane = tid & 63;
    const int w    = tid >> 6;
    const int wm   = w >> 2, wn = w & 3;
    const int fr   = lane & 15, fq = lane >> 4;

    const int nwg = gridDim.x * gridDim.y;
    int flat = blockIdx.y * gridDim.x + blockIdx.x;
    flat = (flat & 7) * (nwg >> 3) + (flat >> 3);
    const int bx = flat % gridDim.x, by = flat / gridDim.x;
    const int m0 = by * 256, n0 = bx * 256;
    const int NT = K >> 5;

    const __hip_bfloat16* aS[2];
    const __hip_bfloat16* bS[2];
    #pragma unroll
    for (int j = 0; j < 2; ++j) {
        const int c   = tid + 512 * j;
        const int row = c >> 2;
        const int lc  = (c & 3) ^ ((row >> 1) & 3);
        aS[j] = A  + (size_t)(m0 + row) * K + lc * 8;
        bS[j] = Bt + (size_t)(n0 + row) * K + lc * 8;
    }

    auto stageA = [&](int kt) {
        __hip_bfloat16* L = &lds[(kt & 3) * SLOT];
        #pragma unroll
        for (int j = 0; j < 2; ++j)
            __builtin_amdgcn_global_load_lds((gas_ptr)(const void*)(aS[j] + kt * 32),
                                             (las_ptr)(void*)(L + w * 512 + j * 4096), 16, 0, 0);
    };
    auto stageB = [&](int kt) {
        __hip_bfloat16* L = &lds[(kt & 3) * SLOT] + 8192;
        #pragma unroll
        for (int j = 0; j < 2; ++j)
            __builtin_amdgcn_global_load_lds((gas_ptr)(const void*)(bS[j] + kt * 32),
                                             (las_ptr)(void*)(L + w * 512 + j * 4096), 16, 0, 0);
    };

    f32x4 acc[8][4] = {};

    stageA(0); stageB(0);
    stageA(1); stageB(1);
    stageA(2); stageB(2);
    asm volatile("s_waitcnt vmcnt(8)" ::: "memory");
    __builtin_amdgcn_s_barrier();
    __builtin_amdgcn_sched_barrier(0);

    for (int kt = 0; kt < NT; ++kt) {
        const __hip_bfloat16* LA = &lds[(kt & 3) * SLOT];
        const __hip_bfloat16* LB = LA + 8192;
        bf16x8 af[4], bg[4];

        #pragma unroll
        for (int m = 0; m < 4; ++m) {
            const int r = wm * 128 + m * 16 + fr;
            af[m] = *reinterpret_cast<const bf16x8*>(
                &LA[r * 32 + ((fq ^ ((r >> 1) & 3)) << 3)]);
        }
        #pragma unroll
        for (int n = 0; n < 4; ++n) {
            const int r = wn * 64 + n * 16 + fr;
            bg[n] = *reinterpret_cast<const bf16x8*>(
                &LB[r * 32 + ((fq ^ ((r >> 1) & 3)) << 3)]);
        }
        if (kt + 3 < NT) stageA(kt + 3);
        __builtin_amdgcn_sched_barrier(0);
        __builtin_amdgcn_s_barrier();
        asm volatile("s_waitcnt lgkmcnt(0)" ::: "memory");
        __builtin_amdgcn_sched_barrier(0);
        __builtin_amdgcn_s_setprio(1);
        #pragma unroll
        for (int m = 0; m < 4; ++m)
            #pragma unroll
            for (int n = 0; n < 4; ++n)
                acc[m][n] = MFMA16(af[m], bg[n], acc[m][n]);
        __builtin_amdgcn_s_setprio(0);
        __builtin_amdgcn_sched_barrier(0);
        __builtin_amdgcn_s_barrier();

        #pragma unroll
        for (int m = 0; m < 4; ++m) {
            const int r = wm * 128 + 64 + m * 16 + fr;
            af[m] = *reinterpret_cast<const bf16x8*>(
                &LA[r * 32 + ((fq ^ ((r >> 1) & 3)) << 3)]);
        }
        if (kt + 3 < NT) stageB(kt + 3);
        __builtin_amdgcn_sched_barrier(0);
        __builtin_amdgcn_s_barrier();
        asm volatile("s_waitcnt lgkmcnt(0)" ::: "memory");
        __builtin_amdgcn_sched_barrier(0);
        __builtin_amdgcn_s_setprio(1);
        #pragma unroll
        for (int m = 0; m < 4; ++m)
            #pragma unroll
            for (int n = 0; n < 4; ++n)
                acc[4 + m][n] = MFMA16(af[m], bg[n], acc[4 + m][n]);
        __builtin_amdgcn_s_setprio(0);
        __builtin_amdgcn_sched_barrier(0);
        if (kt + 3 < NT)      asm volatile("s_waitcnt vmcnt(8)" ::: "memory");
        else if (kt + 2 < NT) asm volatile("s_waitcnt vmcnt(4)" ::: "memory");
        else                  asm volatile("s_waitcnt vmcnt(0)" ::: "memory");
        __builtin_amdgcn_s_barrier();
    }

    __syncthreads();
    ushort* E = reinterpret_cast<ushort*>(lds);
    auto eaddr = [](int r, int c16) { return r * 256 + (((c16) ^ (r & 31)) << 3); };

    #pragma unroll
    for (int n = 0; n < 4; ++n) {
        const int col = wn * 64 + n * 16 + fr;
        const float bv = bias[n0 + col];
        #pragma unroll
        for (int a = 0; a < 8; ++a) {
            #pragma unroll
            for (int i = 0; i < 4; ++i) {
                const int row = wm * 128 + (a >> 2) * 64 + (a & 3) * 16 + fq * 4 + i;
                float v = acc[a][n][i] + bv;
                v = 0.5f * v * (1.0f + erff(v * 0.70710678118654752f));
                E[eaddr(row, col >> 3) + (col & 7)] =
                    __bfloat16_as_ushort(__float2bfloat16(v));
            }
        }
    }
    __syncthreads();

    #pragma unroll
    for (int p = 0; p < 16; ++p) {
        const int id  = p * 512 + tid;
        const int row = id >> 5;
        const int c16 = id & 31;
        const bf16x8 vv = *reinterpret_cast<const bf16x8*>(&E[eaddr(row, c16)]);
        *reinterpret_cast<bf16x8*>(&C0[(size_t)(m0 + row) * N + n0 + c16 * 8]) = vv;
    }
}

// ---------------------------------------------------------------------------
// gemm_n64: 128x64 tile for the grid-starved N=1024 GEMMs (proj, FFN2).
// ---------------------------------------------------------------------------
__global__ __launch_bounds__(256, 3)
void gemm_n64(const __hip_bfloat16* __restrict__ A,
              const __hip_bfloat16* __restrict__ Bt,
              const float* __restrict__ bias,
              const float* __restrict__ resid,
              float* __restrict__ C0,
              int N, int K)
{
    constexpr int SLOT = 6144;
    __shared__ __align__(16) __hip_bfloat16 lds[3 * SLOT];

    const int tid  = threadIdx.x;
    const int lane = tid & 63;
    const int w    = tid >> 6;
    const int wr   = w >> 1, wc = w & 1;
    const int fr   = lane & 15, fq = lane >> 4;

    const int nwg = gridDim.x * gridDim.y;
    int flat = blockIdx.y * gridDim.x + blockIdx.x;
    flat = (flat & 7) * (nwg >> 3) + (flat >> 3);
    const int bx = flat % gridDim.x, by = flat / gridDim.x;
    const int m0 = by * 128, n0 = bx * 64;
    const int NT = K >> 5;

    const int prc = w * 8 + (lane >> 3);
    const int ch  = lane & 7;
    const __hip_bfloat16* aS[2];
    #pragma unroll
    for (int j = 0; j < 2; ++j) {
        const int pr  = prc + 32 * j;
        const int v   = ch ^ (pr & 7);
        aS[j] = A + (size_t)(m0 + 2 * pr + (v >> 2)) * K + 8 * (v & 3);
    }
    const __hip_bfloat16* bS;
    {
        const int c  = w * 64 + lane;
        const int pr = c >> 3;
        const int v  = (c & 7) ^ (pr & 7);
        bS = Bt + (size_t)(n0 + 2 * pr + (v >> 2)) * K + 8 * (v & 3);
    }

    auto stage = [&](int kt, int s) {
        __hip_bfloat16* LA = &lds[s * SLOT];
        __hip_bfloat16* LB = LA + 4096;
        #pragma unroll
        for (int j = 0; j < 2; ++j)
            __builtin_amdgcn_global_load_lds((gas_ptr)(const void*)(aS[j] + kt * 32),
                                             (las_ptr)(void*)(LA + w * 512 + j * 2048), 16, 0, 0);
        __builtin_amdgcn_global_load_lds((gas_ptr)(const void*)(bS + kt * 32),
                                         (las_ptr)(void*)(LB + w * 512), 16, 0, 0);
    };

    f32x4 acc[4][2] = {};

    stage(0, 0);
    stage(1, 1);
    int sl = 0, sp = 2;

    for (int kt = 0; kt < NT; ++kt) {
        if (kt + 1 < NT)
            asm volatile("s_waitcnt vmcnt(3) lgkmcnt(0)" ::: "memory");
        else
            asm volatile("s_waitcnt vmcnt(0) lgkmcnt(0)" ::: "memory");
        __builtin_amdgcn_s_barrier();
        __builtin_amdgcn_sched_barrier(0);

        if (kt + 2 < NT) stage(kt + 2, sp);

        const __hip_bfloat16* LA = &lds[sl * SLOT];
        const __hip_bfloat16* LB = LA + 4096;
        bf16x8 af[4], bg[2];
        #pragma unroll
        for (int m = 0; m < 4; ++m) {
            const int r = wr * 64 + m * 16 + fr;
            af[m] = *reinterpret_cast<const bf16x8*>(
                &LA[(r >> 1) * 64 + (((r & 1) * 32 + fq * 8) ^ (((r >> 1) & 7) * 8))]);
        }
        #pragma unroll
        for (int n = 0; n < 2; ++n) {
            const int r = wc * 32 + n * 16 + fr;
            bg[n] = *reinterpret_cast<const bf16x8*>(
                &LB[(r >> 1) * 64 + (((r & 1) * 32 + fq * 8) ^ (((r >> 1) & 7) * 8))]);
        }

        __builtin_amdgcn_s_setprio(1);
        #pragma unroll
        for (int m = 0; m < 4; ++m)
            #pragma unroll
            for (int n = 0; n < 2; ++n)
                acc[m][n] = MFMA16(af[m], bg[n], acc[m][n]);
        __builtin_amdgcn_s_setprio(0);

        sl = (sl == 2) ? 0 : sl + 1;
        sp = (sp == 2) ? 0 : sp + 1;
    }

    #pragma unroll
    for (int n = 0; n < 2; ++n) {
        const int col = n0 + wc * 32 + n * 16 + fr;
        const float bv = bias[col];
        #pragma unroll
        for (int m = 0; m < 4; ++m)
            #pragma unroll
            for (int i = 0; i < 4; ++i) {
                const int row = m0 + wr * 64 + m * 16 + fq * 4 + i;
                C0[(size_t)row * N + col] = acc[m][n][i] + bv + resid[(size_t)row * N + col];
            }
    }
}

// ---------------------------------------------------------------------------
// Causal flash attention (R10 inner loop) with PAIRED q-tiles for perfect
// load balance: block handles q-tile (31-pr) then (pr) -> 33 kv-tile iters
// per block, uniform. Grid 512 = exactly 2 blocks/CU, zero tail.
// ---------------------------------------------------------------------------
__global__ __launch_bounds__(256)
void attn_kernel(const __hip_bfloat16* __restrict__ qk,
                 const __hip_bfloat16* __restrict__ Vt,
                 __hip_bfloat16* __restrict__ out)
{
    const int bid  = blockIdx.x;             // 0..511
    const int xcd  = bid & 7;
    const int rank = bid >> 3;                // 0..63
    const int panel = xcd * 4 + (rank & 3);   // 0..31
    const int pr   = rank >> 2;               // 0..15 (pair index)
    const int h = panel & 15, b = panel >> 4;

    const int lane = threadIdx.x & 63;
    const int w    = threadIdx.x >> 6;
    const int fr   = lane & 15, fq = lane >> 4;

    __shared__ __align__(16) __hip_bfloat16 Klds[2][64 * 64];
    __shared__ __align__(16) __hip_bfloat16 Vlds[2][64 * 64];

    // staging source pointers (independent of q-tile)
    const int srow8 = lane >> 3;
    const int sc    = lane & 7;
    const __hip_bfloat16* Kg[2];
    const __hip_bfloat16* Vg[2];
    #pragma unroll
    for (int j = 0; j < 2; ++j) {
        const int r = w * 16 + j * 8 + srow8;
        const int csw = (sc ^ (r & 7)) * 8;
        Kg[j] = qk + ((size_t)(b * 2048 + r) << 11) + 1024 + h * 64 + csw;
        Vg[j] = Vt + ((size_t)(b * 1024 + h * 64 + r) << 11) + csw;
    }

    auto stage = [&](int kv0, int bufi) {
        __hip_bfloat16* KL = &Klds[bufi][0];
        __hip_bfloat16* VL = &Vlds[bufi][0];
        #pragma unroll
        for (int j = 0; j < 2; ++j) {
            __builtin_amdgcn_global_load_lds(
                (gas_ptr)(const void*)(Kg[j] + ((size_t)kv0 << 11)),
                (las_ptr)(void*)&KL[(w * 16 + j * 8) * 64], 16, 0, 0);
            __builtin_amdgcn_global_load_lds(
                (gas_ptr)(const void*)(Vg[j] + kv0),
                (las_ptr)(void*)&VL[(w * 16 + j * 8) * 64], 16, 0, 0);
        }
    };

    for (int half = 0; half < 2; ++half) {
        const int qt = half ? pr : (31 - pr);
        const int q0 = qt * 64;
        const int qrow = q0 + w * 16 + fr;

        bf16x8 qf[2];
        {
            const __hip_bfloat16* qp =
                qk + ((size_t)(b * 2048 + qrow) << 11) + h * 64 + fq * 8;
            qf[0] = *reinterpret_cast<const bf16x8*>(qp);
            qf[1] = *reinterpret_cast<const bf16x8*>(qp + 32);
        }

        float m_run = -1e30f, l_run = 0.0f;
        f32x4 o[4] = {};

        const int ntiles = qt + 1;
        if (half) __syncthreads();   // prior half's LDS reads complete
        stage(0, 0);
        int cur = 0;

        for (int t = 0; t < ntiles; ++t) {
            const int kv0 = t << 6;
            __syncthreads();
            if (t + 1 < ntiles) stage((t + 1) << 6, cur ^ 1);

            const __hip_bfloat16* Kl = &Klds[cur][0];
            const __hip_bfloat16* Vl = &Vlds[cur][0];

            f32x4 s[4] = {};
            #pragma unroll
            for (int n = 0; n < 4; ++n) {
                const int row = n * 16 + fr;
                const int sw = (row & 7) << 3;
                const bf16x8 k0 = *reinterpret_cast<const bf16x8*>(&Kl[row * 64 + ((fq * 8) ^ sw)]);
                const bf16x8 k1 = *reinterpret_cast<const bf16x8*>(&Kl[row * 64 + ((fq * 8 + 32) ^ sw)]);
                s[n] = MFMA16(k0, qf[0], s[n]);
                s[n] = MFMA16(k1, qf[1], s[n]);
            }

            // scale folded into Q; mask only on diagonal tile
            float pm = -1e30f;
            if (t == ntiles - 1) {
                #pragma unroll
                for (int n = 0; n < 4; ++n)
                    #pragma unroll
                    for (int i = 0; i < 4; ++i) {
                        const int kvp = kv0 + n * 16 + fq * 4 + i;
                        float sv = s[n][i];
                        sv = (kvp <= qrow) ? sv : -1e30f;
                        s[n][i] = sv;
                        pm = fmaxf(pm, sv);
                    }
            } else {
                #pragma unroll
                for (int n = 0; n < 4; ++n)
                    #pragma unroll
                    for (int i = 0; i < 4; ++i)
                        pm = fmaxf(pm, s[n][i]);
            }
            pm = fmaxf(pm, __shfl_xor(pm, 16));
            pm = fmaxf(pm, __shfl_xor(pm, 32));

            // defer-max: rescale only when running max grew past THR=8
            if (!__all(pm <= m_run + 8.0f)) {
                const float mnew = fmaxf(m_run, pm);
                const float corr = exp2f(m_run - mnew);
                m_run = mnew;
                l_run *= corr;
                #pragma unroll
                for (int i = 0; i < 4; ++i) {
                    const float ci = __shfl(corr, fq * 4 + i);
                    o[0][i] *= ci; o[1][i] *= ci; o[2][i] *= ci; o[3][i] *= ci;
                }
            }

            float rs = 0.0f;
            unsigned pk[8];
            #pragma unroll
            for (int n = 0; n < 4; ++n) {
                const float p0 = exp2f(s[n][0] - m_run);
                const float p1 = exp2f(s[n][1] - m_run);
                const float p2 = exp2f(s[n][2] - m_run);
                const float p3 = exp2f(s[n][3] - m_run);
                rs += (p0 + p1) + (p2 + p3);
                pk[n * 2 + 0] = pack_bf16(p0, p1);
                pk[n * 2 + 1] = pack_bf16(p2, p3);
            }
            rs += __shfl_xor(rs, 16);
            rs += __shfl_xor(rs, 32);
            l_run += rs;

            u32x4 A0, A1;
            #pragma unroll
            for (int r = 0; r < 4; ++r) {
                const int slx = fr + ((2 * (fq & 1) + (r >> 1)) << 4);
                const unsigned lo0 = __shfl(pk[0 + (r & 1)], slx);
                const unsigned hi0 = __shfl(pk[2 + (r & 1)], slx);
                const unsigned lo1 = __shfl(pk[4 + (r & 1)], slx);
                const unsigned hi1 = __shfl(pk[6 + (r & 1)], slx);
                A0[r] = (fq & 2) ? hi0 : lo0;
                A1[r] = (fq & 2) ? hi1 : lo1;
            }
            const bf16x8 pa0 = __builtin_bit_cast(bf16x8, A0);
            const bf16x8 pa1 = __builtin_bit_cast(bf16x8, A1);

            #pragma unroll
            for (int tt = 0; tt < 4; ++tt) {
                const int row = tt * 16 + fr;
                const int sw = (row & 7) << 3;
                const bf16x8 v0 = *reinterpret_cast<const bf16x8*>(&Vl[row * 64 + ((fq * 8) ^ sw)]);
                const bf16x8 v1 = *reinterpret_cast<const bf16x8*>(&Vl[row * 64 + ((fq * 8 + 32) ^ sw)]);
                o[tt] = MFMA16(pa0, v0, o[tt]);
                o[tt] = MFMA16(pa1, v1, o[tt]);
            }
            cur ^= 1;
        }

        #pragma unroll
        for (int i = 0; i < 4; ++i) {
            const float li  = __shfl(l_run, fq * 4 + i);
            const float inv = 1.0f / li;
            const int row = q0 + w * 16 + fq * 4 + i;
            #pragma unroll
            for (int tt = 0; tt < 4; ++tt)
                out[(size_t)(b * 2048 + row) * 1024 + h * 64 + tt * 16 + fr] =
                    __float2bfloat16(o[tt][i] * inv);
        }
    }
}

// ---------------------------------------------------------------------------
extern "C" void kernel_launch(void* const* d_in, const int* in_sizes, int n_in,
                              void* d_out, int out_size, void* d_ws, size_t ws_size,
                              hipStream_t stream)
{
    (void)in_sizes; (void)n_in; (void)out_size; (void)ws_size;
    const float* x      = (const float*)d_in[0];
    const float* ln1_w  = (const float*)d_in[2];
    const float* ln1_b  = (const float*)d_in[3];
    const float* qkv_w  = (const float*)d_in[4];
    const float* qkv_b  = (const float*)d_in[5];
    const float* proj_w = (const float*)d_in[6];
    const float* proj_b = (const float*)d_in[7];
    const float* ln2_w  = (const float*)d_in[8];
    const float* ln2_b  = (const float*)d_in[9];
    const float* ffn_w1 = (const float*)d_in[10];
    const float* ffn_b1 = (const float*)d_in[11];
    const float* ffn_w2 = (const float*)d_in[12];
    const float* ffn_b2 = (const float*)d_in[13];
    float* outp = (float*)d_out;

    char* ws = (char*)d_ws;
    size_t off = 0;
    auto take = [&](size_t bytes) -> char* {
        char* p = ws + off;
        off += (bytes + 255) & ~(size_t)255;
        return p;
    };
    __hip_bfloat16* wqkv  = (__hip_bfloat16*)take((size_t)3072 * 1024 * 2);  // 6 MB
    __hip_bfloat16* wproj = (__hip_bfloat16*)take((size_t)1024 * 1024 * 2);  // 2 MB
    __hip_bfloat16* wff1  = (__hip_bfloat16*)take((size_t)4096 * 1024 * 2);  // 8 MB
    __hip_bfloat16* wff2  = (__hip_bfloat16*)take((size_t)1024 * 4096 * 2);  // 8 MB
    float*          hbuf  = (float*)take((size_t)4096 * 1024 * 4);           // 16 MB
    __hip_bfloat16* xn    = (__hip_bfloat16*)take((size_t)4096 * 1024 * 2);  // 8 MB
    __hip_bfloat16* qkb   = (__hip_bfloat16*)take((size_t)4096 * 2048 * 2);  // 16 MB
    __hip_bfloat16* Vt    = (__hip_bfloat16*)take((size_t)2048 * 2048 * 2);  // 8 MB
    __hip_bfloat16* attn  = (__hip_bfloat16*)take((size_t)4096 * 1024 * 2);  // 8 MB
    __hip_bfloat16* ffn1  = qkb;  // FFN1 out (32 MB) reuses qkb+Vt+attn

    transpose_all<<<12288, 256, 0, stream>>>(qkv_w, proj_w, ffn_w1, ffn_w2,
                                             wqkv, wproj, wff1, wff2);
    // LN1
    ln_kernel<<<4096, 256, 0, stream>>>(x, ln1_w, ln1_b, xn);
    // QKV (q pre-scaled by QK_SCALE; q|k -> qkb, V^T -> Vt)
    gemm128p<3><<<dim3(24, 32), 256, 0, stream>>>(
        xn, wqkv, qkv_b, qkb, Vt, 3072, 1024);
    // Attention (paired q-tiles, uniform 33 iters/block, 512 blocks)
    attn_kernel<<<512, 256, 0, stream>>>(qkb, Vt, attn);
    // proj + residual(x) -> h (fp32)
    gemm_n64<<<dim3(16, 32), 256, 0, stream>>>(
        attn, wproj, proj_b, x, hbuf, 1024, 1024);
    // LN2 -> y
    ln_kernel<<<4096, 256, 0, stream>>>(hbuf, ln2_w, ln2_b, xn);
    // FFN1 + exact GELU (256² pipelined core + staged epilogue)
    gemm256g<<<dim3(16, 16), 512, 0, stream>>>(
        xn, wff1, ffn_b1, ffn1, 4096, 1024);
    // FFN2 + bias + residual(h) -> out (fp32)
    gemm_n64<<<dim3(16, 32), 256, 0, stream>>>(
        ffn1, wff2, ffn_b2, hbuf, outp, 1024, 4096);
}